// Round 1
// baseline (8186.636 us; speedup 1.0000x reference)
//
#include <hip/hip_runtime.h>
#include <math.h>

constexpr int B_   = 64;
constexpr int T_   = 512;
constexpr int D_   = 512;
constexpr int H_   = 1024;
constexpr int IMG_ = 2048;
constexpr int NWG  = 256;
constexpr int NTHR = 256;
constexpr int KTOT = D_ + H_;   // 1536

typedef __attribute__((ext_vector_type(8)))  short          short8;
typedef __attribute__((ext_vector_type(16))) float          f32x16;
typedef __attribute__((ext_vector_type(4)))  unsigned short ushort4v;
typedef __attribute__((ext_vector_type(8)))  unsigned short ushort8v;

__device__ __forceinline__ unsigned short f2bf(float f) {
  unsigned u = __float_as_uint(f);
  u += 0x7FFFu + ((u >> 16) & 1u);     // round-to-nearest-even
  return (unsigned short)(u >> 16);
}

__device__ __forceinline__ float sigf(float v) {
  return 1.0f / (1.0f + __expf(-v));
}

// Persistent multimodal-LSTM kernel.
// Grid: 256 WGs x 256 threads, exactly 1 WG/CU (LDS-limited), grid barrier/step.
// WG (rg, cg): batch rows [rg*32, rg*32+32), h-cols [cg*8, cg*8+8) (x4 gates).
__global__ void __launch_bounds__(NTHR, 1)
mmlstm_persistent(const float* __restrict__ x,
                  const float* __restrict__ img,
                  const float* __restrict__ W_ih,
                  const float* __restrict__ W_hh,
                  const float* __restrict__ b_ih,
                  const float* __restrict__ b_hh,
                  const float* __restrict__ W_m,
                  float* __restrict__ out,
                  float* __restrict__ hn,
                  float* __restrict__ cn,
                  unsigned* __restrict__ bar,
                  unsigned short* __restrict__ Ah0,
                  unsigned short* __restrict__ Ah1)
{
  __shared__ unsigned short Wlds[32 * KTOT];   // 96 KiB: 32 gate rows x 1536 K, bf16, swizzled
  __shared__ unsigned short Axlds[32 * 512];   // 32 KiB: A-panel chunk (32 rows x K=512), swizzled
  __shared__ float gaccs[4][32][33];           // 16.5 KiB: per-wave partial gate accs
  __shared__ float bias_lds[32];

  const int tid  = threadIdx.x;
  const int lane = tid & 63;
  const int wv   = tid >> 6;
  const int wg   = blockIdx.x;
  const int rgid = wg & 1;
  const int cgid = wg >> 1;
  const int brow0 = rgid * 32;
  const int j0    = cgid * 8;

  // ---- stage W slice (32 gate rows = 4 gates x 8 h-cols) into LDS, bf16, XOR-swizzled ----
  // local col c = g*8 + jj  ->  W row g*1024 + j0 + jj ; K: [0,512)=W_ih, [512,1536)=W_hh
  for (int c = 0; c < 32; ++c) {
    const int grow = (c >> 3) * H_ + j0 + (c & 7);
    const int sw   = (c & 15) << 3;
    for (int k = tid; k < KTOT; k += NTHR) {
      const float w = (k < D_) ? W_ih[(size_t)grow * D_ + k]
                               : W_hh[(size_t)grow * H_ + (k - D_)];
      Wlds[c * KTOT + (k ^ sw)] = f2bf(w);
    }
  }
  if (tid < 32) {
    const int grow = (tid >> 3) * H_ + j0 + (tid & 7);
    bias_lds[tid] = b_ih[grow] + b_hh[grow];
  }

  // ---- per-thread ownership: thread = (b_l, jj) -> (b, j); c-state in a VGPR ----
  const int b_l = tid >> 3;
  const int jj  = tid & 7;
  const int b   = brow0 + b_l;
  const int j   = j0 + jj;

  // multimodal gate d[b][j] = img[b] . W_m[j]  (fp32, one dot per thread)
  float dval = 0.0f;
  {
    const float4* ir = (const float4*)(img + (size_t)b * IMG_);
    const float4* wr = (const float4*)(W_m + (size_t)j * IMG_);
    for (int k = 0; k < IMG_ / 4; ++k) {
      const float4 a = ir[k];
      const float4 w = wr[k];
      dval += a.x * w.x + a.y * w.y + a.z * w.z + a.w * w.w;
    }
  }

  // h0 * d = 0
  Ah0[(size_t)b * H_ + j] = 0;

  float  cstate = 0.0f;
  f32x16 acc    = {};

  __syncthreads();   // Wlds/bias ready; Ah0 stores drained before fence below

  // initial arrive (publishes Ah0 zeros)
  if (tid == 0) {
    __threadfence();
    __hip_atomic_fetch_add(bar, 1u, __ATOMIC_RELAXED, __HIP_MEMORY_SCOPE_AGENT);
  }

  unsigned short* Acur  = Ah0;
  unsigned short* Anext = Ah1;
  unsigned wait_target  = NWG;

  // X-projection phase for step t: independent of h -> used to hide barrier latency.
  auto xphase = [&](int t) {
    // stage x[brow0..brow0+32, t, :] -> bf16 swizzled into Axlds
    for (int i = 0; i < 16; ++i) {
      const int idx = i * NTHR + tid;
      const int r   = idx >> 7;          // 128 float4 per row
      const int pos = idx & 127;
      const float4 v = *(const float4*)(x + ((size_t)(brow0 + r) * T_ + t) * D_ + pos * 4);
      ushort4v pk;
      pk.x = f2bf(v.x); pk.y = f2bf(v.y); pk.z = f2bf(v.z); pk.w = f2bf(v.w);
      *(ushort4v*)(Axlds + r * 512 + ((pos * 4) ^ ((r & 15) << 3))) = pk;
    }
    __syncthreads();
    acc = {};
    const int r  = lane & 31;            // doubles as A row and B (gate) col
    const int kh = (lane >> 5) << 3;
    #pragma unroll
    for (int s8 = 0; s8 < 8; ++s8) {     // K-steps s = wv, wv+4, ..., wv+28 (mod-4 split)
      const int kl = (wv + s8 * 4) * 16 + kh;
      const short8 af = *(const short8*)(Axlds + r * 512  + (kl ^ ((r & 15) << 3)));
      const short8 bf = *(const short8*)(Wlds  + r * KTOT + (kl ^ ((r & 15) << 3)));
      acc = __builtin_amdgcn_mfma_f32_32x32x16_bf16(af, bf, acc, 0, 0, 0);
    }
  };

  xphase(0);

  for (int t = 0; t < T_; ++t) {
    // ---- wait for h_t (published by all WGs at end of step t-1) ----
    if (tid == 0) {
      while (__hip_atomic_load(bar, __ATOMIC_RELAXED, __HIP_MEMORY_SCOPE_AGENT) < wait_target)
        __builtin_amdgcn_s_sleep(1);
      __threadfence();   // acquire: invalidate stale L1/L2 lines
    }
    __syncthreads();
    wait_target += NWG;

    // ---- recurrent part: two K=512 chunks of (h*d) ----
    #pragma unroll
    for (int hc = 0; hc < 2; ++hc) {
      for (int i = 0; i < 8; ++i) {
        const int idx = i * NTHR + tid;
        const int r   = idx >> 6;        // 64 x 16B per row
        const int pos = idx & 63;
        const ushort8v v = *(const ushort8v*)(Acur + (size_t)(brow0 + r) * H_ + hc * 512 + pos * 8);
        *(ushort8v*)(Axlds + r * 512 + ((pos * 8) ^ ((r & 15) << 3))) = v;
      }
      __syncthreads();
      {
        const int r  = lane & 31;
        const int kh = (lane >> 5) << 3;
        #pragma unroll
        for (int s8 = 0; s8 < 8; ++s8) {
          const int kloc = (wv + s8 * 4) * 16 + kh;
          const int kglb = D_ + hc * 512 + kloc;
          const short8 af = *(const short8*)(Axlds + r * 512  + (kloc ^ ((r & 15) << 3)));
          const short8 bf = *(const short8*)(Wlds  + r * KTOT + (kglb ^ ((r & 15) << 3)));
          acc = __builtin_amdgcn_mfma_f32_32x32x16_bf16(af, bf, acc, 0, 0, 0);
        }
      }
      __syncthreads();   // before next chunk overwrites Axlds
    }

    // ---- write per-wave partial accs (C/D layout: col=lane&31, row=(r&3)+8*(r>>2)+4*(lane>>5)) ----
    {
      const int colw  = lane & 31;
      const int rbase = (lane >> 5) * 4;
      #pragma unroll
      for (int rr = 0; rr < 16; ++rr) {
        const int row = (rr & 3) + 8 * (rr >> 2) + rbase;
        gaccs[wv][row][colw] = acc[rr];
      }
    }
    __syncthreads();

    // ---- cell update: thread owns (b, j) ----
    float gv[4];
    #pragma unroll
    for (int g = 0; g < 4; ++g) {
      const int c = g * 8 + jj;
      gv[g] = gaccs[0][b_l][c] + gaccs[1][b_l][c] + gaccs[2][b_l][c] + gaccs[3][b_l][c]
            + bias_lds[c];
    }
    const float ig = sigf(gv[0]);
    const float fg = sigf(gv[1]);
    const float gg = tanhf(gv[2]);
    const float og = sigf(gv[3]);
    cstate = fg * cstate + ig * gg;
    const float h = og * tanhf(cstate);
    out[((size_t)b * T_ + t) * H_ + j] = h;
    Anext[(size_t)b * H_ + j] = f2bf(h * dval);   // publish gated h for step t+1
    if (t == T_ - 1) {
      hn[(size_t)b * H_ + j] = h;
      cn[(size_t)b * H_ + j] = cstate;
    }
    __syncthreads();   // drain Anext stores before arrive

    if (t < T_ - 1) {
      if (tid == 0) {
        __threadfence();  // release: wbl2 so other XCDs see Anext
        __hip_atomic_fetch_add(bar, 1u, __ATOMIC_RELAXED, __HIP_MEMORY_SCOPE_AGENT);
      }
      xphase(t + 1);      // h-independent work hides barrier latency
    }
    unsigned short* tmp = Acur; Acur = Anext; Anext = tmp;
  }
}

extern "C" void kernel_launch(void* const* d_in, const int* in_sizes, int n_in,
                              void* d_out, int out_size, void* d_ws, size_t ws_size,
                              hipStream_t stream) {
  (void)in_sizes; (void)n_in; (void)out_size; (void)ws_size;
  const float* x    = (const float*)d_in[0];
  const float* img  = (const float*)d_in[1];
  const float* W_ih = (const float*)d_in[2];
  const float* W_hh = (const float*)d_in[3];
  const float* b_ih = (const float*)d_in[4];
  const float* b_hh = (const float*)d_in[5];
  const float* W_m  = (const float*)d_in[6];

  float* out = (float*)d_out;
  float* hn  = out + (size_t)B_ * T_ * H_;
  float* cn  = hn + (size_t)B_ * H_;

  unsigned*       bar = (unsigned*)d_ws;
  unsigned short* Ah0 = (unsigned short*)((char*)d_ws + 256);
  unsigned short* Ah1 = (unsigned short*)((char*)d_ws + 256 + (size_t)B_ * H_ * 2);

  hipMemsetAsync(d_ws, 0, 256, stream);   // reset grid-barrier counter each call
  hipLaunchKernelGGL(mmlstm_persistent, dim3(NWG), dim3(NTHR), 0, stream,
                     x, img, W_ih, W_hh, b_ih, b_hh, W_m, out, hn, cn, bar, Ah0, Ah1);
}